// Round 12
// baseline (485.778 us; speedup 1.0000x reference)
//
#include <hip/hip_runtime.h>
#include <math.h>

#define N1 8192
#define N2 8192
#define NBATCH 2
#define NBK 512            // candidate buckets per coordinate
#define QBK 1024           // query sort buckets: (mode<<9) | coordbucket
#define QCAP 64            // per-lane survivor capacity (+1 trash row)

typedef unsigned int uint;
typedef unsigned short ushort;
typedef unsigned long long ull;

__device__ __forceinline__ int bux(float x) {
  int b = (int)floorf((x + 4.0f) * 64.0f);
  return min(max(b, 0), NBK - 1);
}
__device__ __forceinline__ int bur(float r) {
  int b = (int)floorf(r * 64.0f);
  return min(max(b, 0), NBK - 1);
}
// Insert key into ascending sorted 16-array (branchless bubble).
__device__ __forceinline__ void ins16(ull* K, ull key) {
  #pragma unroll
  for (int s = 0; s < 16; ++s) {
    bool lt = key < K[s];
    ull mn = lt ? key : K[s];
    ull mx = lt ? K[s] : key;
    K[s] = mn;
    key = mx;
  }
}
template <int J>
__device__ __forceinline__ int lx_i(int x) {
  if constexpr (J == 1)
    return __builtin_amdgcn_update_dpp(x, x, 0xB1, 0xf, 0xf, false);  // [1,0,3,2]
  else if constexpr (J == 2)
    return __builtin_amdgcn_update_dpp(x, x, 0x4E, 0xf, 0xf, false);  // [2,3,0,1]
  else
    return __builtin_amdgcn_ds_swizzle(x, (J << 10) | 0x1F);          // xor<=31
}
template <int J>
__device__ __forceinline__ ull lxu64(ull k) {
  uint lo = (uint)k, hi = (uint)(k >> 32);
  lo = (uint)lx_i<J>((int)lo);
  hi = (uint)lx_i<J>((int)hi);
  return ((ull)hi << 32) | lo;
}
__device__ __forceinline__ int wmax(int v) {
  #pragma unroll
  for (int o = 32; o; o >>= 1) v = max(v, __shfl_xor(v, o));
  return v;
}
// Bitonic merge with lane^J partner: both lanes end with identical lowest-16.
template <int J>
__device__ __forceinline__ void merge_level(ull* K) {
  ull M[16];
  #pragma unroll
  for (int s = 0; s < 16; ++s) {
    ull bk = lxu64<J>(K[15 - s]);
    M[s] = (K[s] < bk) ? K[s] : bk;
  }
#define CEK(i, j) { ull a_ = M[i], c_ = M[j]; \
                    M[i] = (a_ < c_) ? a_ : c_; M[j] = (a_ < c_) ? c_ : a_; }
  CEK(0, 8) CEK(1, 9) CEK(2, 10) CEK(3, 11)
  CEK(4, 12) CEK(5, 13) CEK(6, 14) CEK(7, 15)
  CEK(0, 4) CEK(1, 5) CEK(2, 6) CEK(3, 7)
  CEK(8, 12) CEK(9, 13) CEK(10, 14) CEK(11, 15)
  CEK(0, 2) CEK(1, 3) CEK(4, 6) CEK(5, 7)
  CEK(8, 10) CEK(9, 11) CEK(12, 14) CEK(13, 15)
  CEK(0, 1) CEK(2, 3) CEK(4, 5) CEK(6, 7)
  CEK(8, 9) CEK(10, 11) CEK(12, 13) CEK(14, 15)
#undef CEK
  #pragma unroll
  for (int s = 0; s < 16; ++s) K[s] = M[s];
}

// ---------- build: candidates sorted by x-bucket AND |p|-bucket; packed flows ----------
__global__ __launch_bounds__(1024) void pw3_build(
    const float* __restrict__ xyz1, const float* __restrict__ flow1,
    float4* __restrict__ sp4x, float4* __restrict__ sp4r,
    float4* __restrict__ f1p, uint* __restrict__ offsx, uint* __restrict__ offsr) {
  __shared__ uint hx[NBK], hr[NBK], sx[NBK], sr[NBK];
  int b = blockIdx.x, t = threadIdx.x;
  if (t < NBK) { hx[t] = 0; hr[t] = 0; }
  __syncthreads();
  const float* x1 = xyz1 + b * 3 * N1;
  const float* f1 = flow1 + b * 3 * N1;
  float px[8], py[8], pz[8];
  int bkx[8], bkr[8];
  #pragma unroll
  for (int r = 0; r < 8; ++r) {
    int m = r * 1024 + t;
    float fx = f1[m], fy = f1[N1 + m], fz = f1[2 * N1 + m];
    px[r] = x1[m] + fx;
    py[r] = x1[N1 + m] + fy;
    pz[r] = x1[2 * N1 + m] + fz;
    f1p[(b << 13) + m] = make_float4(fx, fy, fz, 0.f);
    bkx[r] = bux(px[r]);
    bkr[r] = bur(sqrtf(px[r] * px[r] + py[r] * py[r] + pz[r] * pz[r]));
    atomicAdd(&hx[bkx[r]], 1u);
    atomicAdd(&hr[bkr[r]], 1u);
  }
  __syncthreads();
  uint vx = 0, vr = 0;
  if (t < NBK) { vx = hx[t]; vr = hr[t]; sx[t] = vx; sr[t] = vr; }
  __syncthreads();
  for (int off = 1; off < NBK; off <<= 1) {
    uint ax = 0, ar = 0;
    if (t < NBK && t >= off) { ax = sx[t - off]; ar = sr[t - off]; }
    __syncthreads();
    if (t < NBK) { sx[t] += ax; sr[t] += ar; }
    __syncthreads();
  }
  if (t < NBK) {
    uint ex = sx[t] - vx, er = sr[t] - vr;
    offsx[(b << 9) + t] = ex;
    offsr[(b << 9) + t] = er;
    hx[t] = ex;   // reuse as cursors
    hr[t] = er;
  }
  __syncthreads();
  #pragma unroll
  for (int r = 0; r < 8; ++r) {
    int m = r * 1024 + t;
    float4 v = make_float4(px[r], py[r], pz[r], __int_as_float(m));
    uint p1 = atomicAdd(&hx[bkx[r]], 1u);
    sp4x[(b << 13) + p1] = v;
    uint p2 = atomicAdd(&hr[bkr[r]], 1u);
    sp4r[(b << 13) + p2] = v;
  }
}

// ---------- qprep (grid-wide): per-query radius R + sort key ----------
__global__ __launch_bounds__(256) void pw3_qprep(
    const float* __restrict__ xyz2, const uint* __restrict__ offsx,
    const uint* __restrict__ offsr, int* __restrict__ gkey,
    float* __restrict__ gR) {
  int i = blockIdx.x * 256 + threadIdx.x;   // 0 .. B*N2-1
  int b = i >> 13, n = i & 8191;
  const float* x2 = xyz2 + b * 3 * N2;
  float X = x2[n], Y = x2[N2 + n], Z = x2[2 * N2 + n];
  float rr = X * X + Y * Y + Z * Z;
  const float T = 70.f;             // box target -> ball count ~ 35 >= 16 w.h.p.
  const float IS2 = 0.70360f;       // 1/(sigma*sqrt(2)), sigma^2 = 1.01
  float R = cbrtf(3.2225e-2f * expf(rr * 0.49505f));
  R = fminf(R, 6.f);
  #pragma unroll
  for (int it = 0; it < 4; ++it) {
    float g = 8192.f
      * (0.5f * (erff((X + R) * IS2) - erff((X - R) * IS2)))
      * (0.5f * (erff((Y + R) * IS2) - erff((Y - R) * IS2)))
      * (0.5f * (erff((Z + R) * IS2) - erff((Z - R) * IS2)));
    R = R * cbrtf(T / fmaxf(g, 1.f));
    R = fminf(R, 8.f);
  }
  R *= 1.05f;
  float rl = sqrtf(rr);
  int bxl = bux(X - R), bxh = bux(X + R);
  int brl = bur(rl - R), brh = bur(rl + R);
  uint jx1 = offsx[(b << 9) + bxl];
  uint jx2 = (bxh >= NBK - 1) ? 8192u : offsx[(b << 9) + bxh + 1];
  uint jr1 = offsr[(b << 9) + brl];
  uint jr2 = (brh >= NBK - 1) ? 8192u : offsr[(b << 9) + brh + 1];
  int mode = ((jr2 - jr1) < (jx2 - jx1)) ? 1 : 0;
  int cb = mode ? bur(rl) : bux(X);
  gkey[i] = (mode << 9) | cb;
  gR[i] = R;
}

// ---------- qsort: counting-sort queries by precomputed key ----------
__global__ __launch_bounds__(1024) void pw3_qsort(
    const float* __restrict__ xyz2, const int* __restrict__ gkey,
    const float* __restrict__ gR, float4* __restrict__ qs4,
    float* __restrict__ qR) {
  __shared__ uint hq[QBK], sq[QBK];
  int b = blockIdx.x, t = threadIdx.x;
  hq[t] = 0;
  __syncthreads();
  int key[8];
  #pragma unroll
  for (int r = 0; r < 8; ++r) {
    key[r] = gkey[(b << 13) + r * 1024 + t];
    atomicAdd(&hq[key[r]], 1u);
  }
  __syncthreads();
  uint v = hq[t];
  sq[t] = v;
  __syncthreads();
  for (int off = 1; off < QBK; off <<= 1) {
    uint a = 0;
    if (t >= off) a = sq[t - off];
    __syncthreads();
    sq[t] += a;
    __syncthreads();
  }
  hq[t] = sq[t] - v;   // cursor
  __syncthreads();
  const float* x2 = xyz2 + b * 3 * N2;
  #pragma unroll
  for (int r = 0; r < 8; ++r) {
    int n = r * 1024 + t;
    uint pos = atomicAdd(&hq[key[r]], 1u);
    int mode = key[r] >> 9;
    qs4[(b << 13) + pos] = make_float4(x2[n], x2[N2 + n], x2[2 * N2 + n],
                                       __int_as_float(n | (mode << 13)));
    qR[(b << 13) + pos] = gR[(b << 13) + n];
  }
}

// ---------- sweep: 1 wave = 8 sorted queries x 8 slice-lanes; barrier-free ----------
__global__ __launch_bounds__(256) void pw3_sweep(
    const float4* __restrict__ sp4x, const float4* __restrict__ sp4r,
    const float4* __restrict__ f1p, const uint* __restrict__ offsx,
    const uint* __restrict__ offsr, const float4* __restrict__ qs4,
    const float* __restrict__ qR, float* __restrict__ out) {
  __shared__ ushort surv[(QCAP + 1) * 256];   // [slot][tid]; row QCAP = trash
  int tid = threadIdx.x;
  int lane = tid & 63;
  int s = lane & 7;                  // slice within query octet
  int W = blockIdx.x * 4 + (tid >> 6);   // global wave id, 0..2047
  int b = W >> 10;
  int qpos = ((W & 1023) << 3) + (lane >> 3);   // sorted position in batch

  float4 q = qs4[(b << 13) + qpos];
  int payload = __float_as_int(q.w);
  int n = payload & 8191;
  int mode = (payload >> 13) & 1;    // per-lane
  float X = q.x, Y = q.y, Z = q.z;
  const float4* __restrict__ arr = mode ? sp4r + ((size_t)b << 13)
                                        : sp4x + ((size_t)b << 13);
  const uint* __restrict__ offs = mode ? offsr + (b << 9) : offsx + (b << 9);
  float cc = mode ? sqrtf(X * X + Y * Y + Z * Z) : X;
  float R = qR[(b << 13) + qpos];
  float Rsq = R * R;

  ull K[16];
  #pragma unroll
  for (int t2 = 0; t2 < 16; ++t2) K[t2] = ~0ull;
  int cnt = 0;
  bool alive = true;
  int attempt = 0;
  uint jlo = 0, jhi = 0;

  while (true) {
    if (attempt >= 6) {
      jlo = 0; jhi = 8192; Rsq = INFINITY;
    } else {
      int blo = mode ? bur(cc - R) : bux(cc - R);
      int bhi = mode ? bur(cc + R) : bux(cc + R);
      jlo = offs[blo];
      jhi = (bhi >= NBK - 1) ? 8192u : offs[bhi + 1];
    }
    int steps = alive ? (int)((jhi - jlo + 7u) >> 3) : 0;
    int mxs = wmax(steps);
    uint myb = jlo + (uint)s;
    if (mxs > 0) {
      uint i0 = myb;
      bool ib0 = alive && (i0 < jhi);
      float4 vc = arr[ib0 ? i0 : 0u];
      for (int i = 0; i < mxs; ++i) {
        uint i1 = myb + (uint)((i + 1) << 3);
        bool ib1 = alive && (i1 < jhi) && (i + 1 < mxs);
        float4 vn = arr[ib1 ? i1 : 0u];        // prefetch
        uint idx = myb + (uint)(i << 3);
        bool inb = alive && (idx < jhi);
        float dx = X - vc.x, dy = Y - vc.y, dz = Z - vc.z;
        float d = fmaf(dz, dz, fmaf(dy, dy, dx * dx));
        bool hit = inb && (d <= Rsq);
        surv[min(cnt, QCAP) * 256 + tid] = (ushort)idx;   // branchless
        cnt += hit ? 1 : 0;
        vc = vn;
      }
    }
    // per-query total across its 8 slice-lanes
    int tot = cnt;
    tot += __shfl_xor(tot, 1);
    tot += __shfl_xor(tot, 2);
    tot += __shfl_xor(tot, 4);
    bool fail = alive && (tot < 16) && (attempt < 6);
    if (!__ballot(fail)) break;
    if (fail) { R *= 2.f; Rsq = R * R; cnt = 0; }
    alive = fail;
    attempt++;
  }

  // ---- resolve buffered survivors (per-lane exact top-16) ----
  int lc = (cnt <= QCAP) ? cnt : 0;     // overflow lanes redo from scratch below
  int mx = wmax(lc);
  for (int s2 = 0; s2 < mx; ++s2) {
    uint pos = surv[s2 * 256 + tid] & 8191u;
    float4 v = arr[pos];
    float dx = X - v.x, dy = Y - v.y, dz = Z - v.z;
    float d = fmaf(dz, dz, fmaf(dy, dy, dx * dx));
    ull key = ((ull)__float_as_uint(d) << 32) | (uint)(__float_as_int(v.w) & 8191);
    if (s2 >= lc) key = ~0ull;
    ins16(K, key);
  }
  // ---- rare lossless overflow redo (clear K, rescan own slice with pruning) ----
  if (__builtin_expect(__ballot(cnt > QCAP) != 0ull, 0)) {
    bool need = cnt > QCAP;
    if (need) {
      #pragma unroll
      for (int t2 = 0; t2 < 16; ++t2) K[t2] = ~0ull;
    }
    int steps2 = need ? (int)((jhi - jlo + 7u) >> 3) : 0;
    int mx2 = wmax(steps2);
    for (int i = 0; i < mx2; ++i) {
      uint idx = jlo + (uint)s + (uint)(i << 3);
      bool inb = need && (idx < jhi);
      float4 v = arr[inb ? idx : 0u];
      float dx = X - v.x, dy = Y - v.y, dz = Z - v.z;
      float d = fmaf(dz, dz, fmaf(dy, dy, dx * dx));
      ull key = ((ull)__float_as_uint(d) << 32) | (uint)(__float_as_int(v.w) & 8191);
      if (inb && (d <= Rsq) && (key < K[15])) ins16(K, key);
    }
  }

  // ---- octet merge: 3 bitonic levels; all 8 lanes end identical ----
  merge_level<1>(K);
  merge_level<2>(K);
  merge_level<4>(K);

  if (s == 0) {
    const float4* __restrict__ fp = f1p + ((size_t)b << 13);
    float fx = 0.f, fy = 0.f, fz = 0.f;
    #pragma unroll
    for (int t2 = 0; t2 < 16; ++t2) {
      float4 f = fp[(uint)(K[t2] & 8191u)];
      fx += f.x; fy += f.y; fz += f.z;
    }
    float* op = out + b * 3 * N2;
    op[n]          = X - fx * 0.0625f;
    op[N2 + n]     = Y - fy * 0.0625f;
    op[2 * N2 + n] = Z - fz * 0.0625f;
  }
}

extern "C" void kernel_launch(void* const* d_in, const int* in_sizes, int n_in,
                              void* d_out, int out_size, void* d_ws, size_t ws_size,
                              hipStream_t stream) {
  const float* xyz1  = (const float*)d_in[0];
  const float* xyz2  = (const float*)d_in[1];
  const float* flow1 = (const float*)d_in[2];
  float* out = (float*)d_out;

  char* w = (char*)d_ws;
  float4* sp4x = (float4*)w;  w += (size_t)NBATCH * N1 * sizeof(float4);   // 256 KB
  float4* sp4r = (float4*)w;  w += (size_t)NBATCH * N1 * sizeof(float4);   // 256 KB
  float4* f1p  = (float4*)w;  w += (size_t)NBATCH * N1 * sizeof(float4);   // 256 KB
  float4* qs4  = (float4*)w;  w += (size_t)NBATCH * N2 * sizeof(float4);   // 256 KB
  float* qR    = (float*)w;   w += (size_t)NBATCH * N2 * sizeof(float);    // 64 KB
  int* gkey    = (int*)w;     w += (size_t)NBATCH * N2 * sizeof(int);      // 64 KB
  float* gR    = (float*)w;   w += (size_t)NBATCH * N2 * sizeof(float);    // 64 KB
  uint* offsx  = (uint*)w;    w += NBATCH * NBK * sizeof(uint);            // 4 KB
  uint* offsr  = (uint*)w;    w += NBATCH * NBK * sizeof(uint);            // 4 KB

  pw3_build<<<NBATCH, 1024, 0, stream>>>(xyz1, flow1, sp4x, sp4r, f1p, offsx, offsr);
  pw3_qprep<<<(NBATCH * N2) / 256, 256, 0, stream>>>(xyz2, offsx, offsr, gkey, gR);
  pw3_qsort<<<NBATCH, 1024, 0, stream>>>(xyz2, gkey, gR, qs4, qR);
  pw3_sweep<<<(NBATCH * 1024) / 4, 256, 0, stream>>>(sp4x, sp4r, f1p, offsx, offsr,
                                                     qs4, qR, out);
}

// Round 14
// 219.157 us; speedup vs baseline: 2.2166x; 2.2166x over previous
//
#include <hip/hip_runtime.h>
#include <math.h>

#define N1 8192
#define N2 8192
#define NBATCH 2
#define NBK 512            // candidate buckets per coordinate
#define QBK 1024           // query sort buckets: (mode<<9) | coordbucket

typedef unsigned int uint;
typedef unsigned long long ull;

__device__ __forceinline__ int bux(float x) {
  int b = (int)floorf((x + 4.0f) * 64.0f);
  return min(max(b, 0), NBK - 1);
}
__device__ __forceinline__ int bur(float r) {
  int b = (int)floorf(r * 64.0f);
  return min(max(b, 0), NBK - 1);
}
// DPP shift-up-by-1 within each 16-lane row; lanes 0/16/32/48 receive old.
__device__ __forceinline__ float dpp_up1_f(float x, float old_v) {
  int r = __builtin_amdgcn_update_dpp(
      __builtin_bit_cast(int, old_v), __builtin_bit_cast(int, x),
      0x111, 0xf, 0xf, false);
  return __builtin_bit_cast(float, r);
}
__device__ __forceinline__ int dpp_up1_i(int x) {
  return __builtin_amdgcn_update_dpp(0, x, 0x111, 0xf, 0xf, false);
}

// ---------- build: candidates sorted by x-bucket AND |p|-bucket; packed flows ----------
__global__ __launch_bounds__(1024) void pw3_build(
    const float* __restrict__ xyz1, const float* __restrict__ flow1,
    float4* __restrict__ sp4x, float4* __restrict__ sp4r,
    float4* __restrict__ f1p, uint* __restrict__ offsx, uint* __restrict__ offsr) {
  __shared__ uint hx[NBK], hr[NBK], sx[NBK], sr[NBK];
  int b = blockIdx.x, t = threadIdx.x;
  if (t < NBK) { hx[t] = 0; hr[t] = 0; }
  __syncthreads();
  const float* x1 = xyz1 + b * 3 * N1;
  const float* f1 = flow1 + b * 3 * N1;
  float px[8], py[8], pz[8];
  int bkx[8], bkr[8];
  #pragma unroll
  for (int r = 0; r < 8; ++r) {
    int m = r * 1024 + t;
    float fx = f1[m], fy = f1[N1 + m], fz = f1[2 * N1 + m];
    px[r] = x1[m] + fx;
    py[r] = x1[N1 + m] + fy;
    pz[r] = x1[2 * N1 + m] + fz;
    f1p[(b << 13) + m] = make_float4(fx, fy, fz, 0.f);
    bkx[r] = bux(px[r]);
    bkr[r] = bur(sqrtf(px[r] * px[r] + py[r] * py[r] + pz[r] * pz[r]));
    atomicAdd(&hx[bkx[r]], 1u);
    atomicAdd(&hr[bkr[r]], 1u);
  }
  __syncthreads();
  uint vx = 0, vr = 0;
  if (t < NBK) { vx = hx[t]; vr = hr[t]; sx[t] = vx; sr[t] = vr; }
  __syncthreads();
  for (int off = 1; off < NBK; off <<= 1) {
    uint ax = 0, ar = 0;
    if (t < NBK && t >= off) { ax = sx[t - off]; ar = sr[t - off]; }
    __syncthreads();
    if (t < NBK) { sx[t] += ax; sr[t] += ar; }
    __syncthreads();
  }
  if (t < NBK) {
    uint ex = sx[t] - vx, er = sr[t] - vr;
    offsx[(b << 9) + t] = ex;
    offsr[(b << 9) + t] = er;
    hx[t] = ex;   // reuse as cursors
    hr[t] = er;
  }
  __syncthreads();
  #pragma unroll
  for (int r = 0; r < 8; ++r) {
    int m = r * 1024 + t;
    float4 v = make_float4(px[r], py[r], pz[r], __int_as_float(m));
    uint p1 = atomicAdd(&hx[bkx[r]], 1u);
    sp4x[(b << 13) + p1] = v;
    uint p2 = atomicAdd(&hr[bkr[r]], 1u);
    sp4r[(b << 13) + p2] = v;
  }
}

// ---------- qprep (grid-wide): per-query radius R + sort key ----------
__global__ __launch_bounds__(256) void pw3_qprep(
    const float* __restrict__ xyz2, const uint* __restrict__ offsx,
    const uint* __restrict__ offsr, int* __restrict__ gkey,
    float* __restrict__ gR) {
  int i = blockIdx.x * 256 + threadIdx.x;   // 0 .. B*N2-1
  int b = i >> 13, n = i & 8191;
  const float* x2 = xyz2 + b * 3 * N2;
  float X = x2[n], Y = x2[N2 + n], Z = x2[2 * N2 + n];
  float rr = X * X + Y * Y + Z * Z;
  const float T = 70.f;             // box target -> ball count ~ 37 >= 16 w.h.p.
  const float IS2 = 0.70360f;       // 1/(sigma*sqrt(2)), sigma^2 = 1.01
  float R = cbrtf(3.2225e-2f * expf(rr * 0.49505f));
  R = fminf(R, 6.f);
  #pragma unroll
  for (int it = 0; it < 4; ++it) {
    float g = 8192.f
      * (0.5f * (erff((X + R) * IS2) - erff((X - R) * IS2)))
      * (0.5f * (erff((Y + R) * IS2) - erff((Y - R) * IS2)))
      * (0.5f * (erff((Z + R) * IS2) - erff((Z - R) * IS2)));
    R = R * cbrtf(T / fmaxf(g, 1.f));
    R = fminf(R, 8.f);
  }
  R *= 1.05f;
  float rl = sqrtf(rr);
  int bxl = bux(X - R), bxh = bux(X + R);
  int brl = bur(rl - R), brh = bur(rl + R);
  uint jx1 = offsx[(b << 9) + bxl];
  uint jx2 = (bxh >= NBK - 1) ? 8192u : offsx[(b << 9) + bxh + 1];
  uint jr1 = offsr[(b << 9) + brl];
  uint jr2 = (brh >= NBK - 1) ? 8192u : offsr[(b << 9) + brh + 1];
  int mode = ((jr2 - jr1) < (jx2 - jx1)) ? 1 : 0;
  int cb = mode ? bur(rl) : bux(X);
  gkey[i] = (mode << 9) | cb;
  gR[i] = R;
}

// ---------- qsort: counting-sort queries by precomputed key ----------
__global__ __launch_bounds__(1024) void pw3_qsort(
    const float* __restrict__ xyz2, const int* __restrict__ gkey,
    const float* __restrict__ gR, float4* __restrict__ qs4,
    float* __restrict__ qR) {
  __shared__ uint hq[QBK], sq[QBK];
  int b = blockIdx.x, t = threadIdx.x;
  hq[t] = 0;
  __syncthreads();
  int key[8];
  #pragma unroll
  for (int r = 0; r < 8; ++r) {
    key[r] = gkey[(b << 13) + r * 1024 + t];
    atomicAdd(&hq[key[r]], 1u);
  }
  __syncthreads();
  uint v = hq[t];
  sq[t] = v;
  __syncthreads();
  for (int off = 1; off < QBK; off <<= 1) {
    uint a = 0;
    if (t >= off) a = sq[t - off];
    __syncthreads();
    sq[t] += a;
    __syncthreads();
  }
  hq[t] = sq[t] - v;   // cursor
  __syncthreads();
  const float* x2 = xyz2 + b * 3 * N2;
  #pragma unroll
  for (int r = 0; r < 8; ++r) {
    int n = r * 1024 + t;
    uint pos = atomicAdd(&hq[key[r]], 1u);
    int mode = key[r] >> 9;
    qs4[(b << 13) + pos] = make_float4(x2[n], x2[N2 + n], x2[2 * N2 + n],
                                       __int_as_float(n | (mode << 13)));
    qR[(b << 13) + pos] = gR[(b << 13) + n];
  }
}

// ---------- knn: one wave per sorted query; slab scan; DPP insert list ----------
__global__ __launch_bounds__(256) void pw3_knn(
    const float4* __restrict__ sp4x, const float4* __restrict__ sp4r,
    const float4* __restrict__ f1p, const uint* __restrict__ offsx,
    const uint* __restrict__ offsr, const float4* __restrict__ qs4,
    const float* __restrict__ qR, float* __restrict__ out) {
  int lane = threadIdx.x & 63;
  int W = (int)((blockIdx.x * 256 + threadIdx.x) >> 6);  // wave id = sorted query
  int b = W >> 13;
  int qpos = W & 8191;

  float4 q = qs4[(b << 13) + qpos];
  int payload = __float_as_int(q.w);
  int n = payload & 8191;
  int mode = (payload >> 13) & 1;          // wave-uniform
  float X = q.x, Y = q.y, Z = q.z;
  const float4* __restrict__ arr = mode ? sp4r + ((size_t)b << 13)
                                        : sp4x + ((size_t)b << 13);
  const uint* __restrict__ offs = mode ? offsr + (b << 9) : offsx + (b << 9);
  float cc = mode ? sqrtf(X * X + Y * Y + Z * Z) : X;
  float R = qR[(b << 13) + qpos];
  float Rsq = R * R;

  const float NEG_INF = -INFINITY;
  float val = INFINITY;   // distributed sorted top-16 per 16-lane row (x4 replicas)
  int vidx = 0;
  int attempt = 0;

  while (true) {
    int blo = mode ? bur(cc - R) : bux(cc - R);
    int bhi = mode ? bur(cc + R) : bux(cc + R);
    uint jlo = offs[blo];
    uint jhi = (bhi >= NBK - 1) ? 8192u : offs[bhi + 1];
    if (attempt >= 5) { jlo = 0; jhi = 8192u; Rsq = INFINITY; }  // guaranteed
    int c0 = (int)(jlo >> 6), c1 = (int)((jhi + 63u) >> 6);
    int cnt = 0;

    float4 vc = arr[c0 * 64 + lane];
    for (int c = c0; c < c1; ++c) {
      int cn = (c + 1 < c1) ? c + 1 : c;
      float4 vn = arr[cn * 64 + lane];       // depth-1 prefetch (coalesced)
      uint i = (uint)(c * 64) + (uint)lane;
      float dx = X - vc.x, dy = Y - vc.y, dz = Z - vc.z;
      float d = fmaf(dz, dz, fmaf(dy, dy, dx * dx));
      bool hit = (i >= jlo) && (i < jhi) && (d <= Rsq);
      ull bal = __ballot(hit);
      cnt += (int)__popcll(bal);
      if (bal) {
        int dbits = __float_as_int(d);
        int ibits = __float_as_int(vc.w);
        do {
          int l = __ffsll((long long)bal) - 1;
          bal &= bal - 1;
          float cd = __int_as_float(__builtin_amdgcn_readlane(dbits, l));
          int ci = __builtin_amdgcn_readlane(ibits, l);
          float pv = dpp_up1_f(val, NEG_INF);
          int pi = dpp_up1_i(vidx);
          bool lt = cd < val;
          bool ltp = cd < pv;
          val = lt ? (ltp ? pv : cd) : val;
          vidx = lt ? (ltp ? pi : ci) : vidx;
        } while (bal);
      }
      vc = vn;
    }

    if (cnt >= 16 || attempt >= 5) break;   // wave-uniform
    attempt++;
    R *= 2.f;
    Rsq = R * R;
    val = INFINITY;
    vidx = 0;
  }

  // gather selected flows (each lane holds one of 16, x4 replica groups)
  const float4* __restrict__ fp = f1p + ((size_t)b << 13);
  float4 f = fp[(uint)vidx & 8191u];
  float fx = f.x, fy = f.y, fz = f.z;
  #pragma unroll
  for (int o = 8; o > 0; o >>= 1) {
    fx += __shfl_xor(fx, o);
    fy += __shfl_xor(fy, o);
    fz += __shfl_xor(fz, o);
  }

  if (lane == 0) {
    float* op = out + b * 3 * N2;
    op[n]          = X - fx * 0.0625f;
    op[N2 + n]     = Y - fy * 0.0625f;
    op[2 * N2 + n] = Z - fz * 0.0625f;
  }
}

extern "C" void kernel_launch(void* const* d_in, const int* in_sizes, int n_in,
                              void* d_out, int out_size, void* d_ws, size_t ws_size,
                              hipStream_t stream) {
  const float* xyz1  = (const float*)d_in[0];
  const float* xyz2  = (const float*)d_in[1];
  const float* flow1 = (const float*)d_in[2];
  float* out = (float*)d_out;

  char* w = (char*)d_ws;
  float4* sp4x = (float4*)w;  w += (size_t)NBATCH * N1 * sizeof(float4);   // 256 KB
  float4* sp4r = (float4*)w;  w += (size_t)NBATCH * N1 * sizeof(float4);   // 256 KB
  float4* f1p  = (float4*)w;  w += (size_t)NBATCH * N1 * sizeof(float4);   // 256 KB
  float4* qs4  = (float4*)w;  w += (size_t)NBATCH * N2 * sizeof(float4);   // 256 KB
  float* qR    = (float*)w;   w += (size_t)NBATCH * N2 * sizeof(float);    // 64 KB
  int* gkey    = (int*)w;     w += (size_t)NBATCH * N2 * sizeof(int);      // 64 KB
  float* gR    = (float*)w;   w += (size_t)NBATCH * N2 * sizeof(float);    // 64 KB
  uint* offsx  = (uint*)w;    w += NBATCH * NBK * sizeof(uint);            // 4 KB
  uint* offsr  = (uint*)w;    w += NBATCH * NBK * sizeof(uint);            // 4 KB

  pw3_build<<<NBATCH, 1024, 0, stream>>>(xyz1, flow1, sp4x, sp4r, f1p, offsx, offsr);
  pw3_qprep<<<(NBATCH * N2) / 256, 256, 0, stream>>>(xyz2, offsx, offsr, gkey, gR);
  pw3_qsort<<<NBATCH, 1024, 0, stream>>>(xyz2, gkey, gR, qs4, qR);
  pw3_knn<<<(NBATCH * N2 * 64) / 256, 256, 0, stream>>>(sp4x, sp4r, f1p, offsx,
                                                        offsr, qs4, qR, out);
}